// Round 1
// baseline (856.438 us; speedup 1.0000x reference)
//
#include <hip/hip_runtime.h>
#include <math.h>

constexpr int B = 4;
constexpr int N = 8192;
constexpr int KNN = 8;

// Prologue: pack pred = src+flow and target as float4 (x, y, z, |p|^2 / 2).
__global__ __launch_bounds__(256) void prep_kernel(
    const float* __restrict__ src, const float* __restrict__ tgt,
    const float* __restrict__ flow, float4* __restrict__ pred4,
    float4* __restrict__ tgt4) {
  int i = blockIdx.x * 256 + threadIdx.x;
  if (i >= B * N) return;
  float px = src[3 * i + 0] + flow[3 * i + 0];
  float py = src[3 * i + 1] + flow[3 * i + 1];
  float pz = src[3 * i + 2] + flow[3 * i + 2];
  pred4[i] = make_float4(px, py, pz, 0.5f * (px * px + py * py + pz * pz));
  float tx = tgt[3 * i + 0];
  float ty = tgt[3 * i + 1];
  float tz = tgt[3 * i + 2];
  tgt4[i] = make_float4(tx, ty, tz, 0.5f * (tx * tx + ty * ty + tz * tz));
}

// One thread per query point. Inner loop streams all 8192 candidates of the
// batch via (wave-uniform -> scalar) loads; each thread maintains a sorted
// top-8 of rank keys t = |p|^2/2 - q.p  (== (d2 - |q|^2)/2, monotone in d2).
__global__ __launch_bounds__(256) void chamfer_kernel(
    const float4* __restrict__ pred4, const float4* __restrict__ tgt4,
    float* __restrict__ out) {
  int blk = blockIdx.x;           // 256 blocks
  int dir = blk >> 7;             // 0: pred->tgt, 1: tgt->pred
  int batch = (blk >> 5) & 3;     // 4 batches
  int chunk = blk & 31;           // 32 chunks of 256 queries
  const float4* __restrict__ qarr = (dir == 0 ? pred4 : tgt4) + batch * N;
  const float4* __restrict__ parr = (dir == 0 ? tgt4 : pred4) + batch * N;

  float4 q = qarr[chunk * 256 + threadIdx.x];

  float d[KNN];
#pragma unroll
  for (int i = 0; i < KNN; ++i) d[i] = INFINITY;

#pragma unroll 4
  for (int j = 0; j < N; ++j) {
    float4 p = parr[j];  // uniform address -> s_load_dwordx4 expected
    float t = __builtin_fmaf(-q.x, p.x,
              __builtin_fmaf(-q.y, p.y,
              __builtin_fmaf(-q.z, p.z, p.w)));
    if (t < d[KNN - 1]) {
      // branchless sorted insertion (uses old d[i-1] before it is updated)
#pragma unroll
      for (int i = KNN - 1; i > 0; --i) d[i] = fminf(d[i], fmaxf(d[i - 1], t));
      d[0] = fminf(d[0], t);
    }
  }

  float q2 = 2.0f * q.w;
  float s = 0.0f;
#pragma unroll
  for (int i = 0; i < KNN; ++i) {
    float d2 = fmaxf(__builtin_fmaf(2.0f, d[i], q2), 0.0f);
    s += sqrtf(d2);
  }
  float val = s * (1.0f / KNN);

  // block reduction: wave64 shuffle, then 4 partials through LDS
  for (int off = 32; off; off >>= 1) val += __shfl_down(val, off, 64);
  __shared__ float red[4];
  int lane = threadIdx.x & 63;
  int wid = threadIdx.x >> 6;
  if (lane == 0) red[wid] = val;
  __syncthreads();
  if (threadIdx.x == 0) {
    float blocksum = red[0] + red[1] + red[2] + red[3];
    // final result = sum(dist1)+sum(dist2) over all queries, / (B*N)
    atomicAdd(out, blocksum * (1.0f / (B * N)));
  }
}

extern "C" void kernel_launch(void* const* d_in, const int* in_sizes, int n_in,
                              void* d_out, int out_size, void* d_ws, size_t ws_size,
                              hipStream_t stream) {
  const float* src = (const float*)d_in[0];
  const float* tgt = (const float*)d_in[1];
  const float* flow = (const float*)d_in[2];
  float* out = (float*)d_out;
  float4* pred4 = (float4*)d_ws;
  float4* tgt4 = pred4 + B * N;

  hipMemsetAsync(d_out, 0, sizeof(float), stream);
  prep_kernel<<<(B * N) / 256, 256, 0, stream>>>(src, tgt, flow, pred4, tgt4);
  chamfer_kernel<<<256, 256, 0, stream>>>(pred4, tgt4, out);
}

// Round 2
// 334.752 us; speedup vs baseline: 2.5584x; 2.5584x over previous
//
#include <hip/hip_runtime.h>
#include <math.h>

constexpr int B = 4;
constexpr int N = 8192;
constexpr int KNN = 8;
constexpr int SLICES = 4;      // candidate slices == waves per block
constexpr int QPB = 64;        // queries per block (one per lane)
constexpr int L = N / SLICES;  // candidates per slice

// Prologue: pack pred = src+flow and target as float4 (x, y, z, |p|^2 / 2).
__global__ __launch_bounds__(256) void prep_kernel(
    const float* __restrict__ src, const float* __restrict__ tgt,
    const float* __restrict__ flow, float4* __restrict__ pred4,
    float4* __restrict__ tgt4) {
  int i = blockIdx.x * 256 + threadIdx.x;
  if (i >= B * N) return;
  float px = src[3 * i + 0] + flow[3 * i + 0];
  float py = src[3 * i + 1] + flow[3 * i + 1];
  float pz = src[3 * i + 2] + flow[3 * i + 2];
  pred4[i] = make_float4(px, py, pz, 0.5f * (px * px + py * py + pz * pz));
  float tx = tgt[3 * i + 0];
  float ty = tgt[3 * i + 1];
  float tz = tgt[3 * i + 2];
  tgt4[i] = make_float4(tx, ty, tz, 0.5f * (tx * tx + ty * ty + tz * tz));
}

// Block = 4 waves. Wave w processes candidate slice w (2048 candidates) for
// 64 queries (one per lane). Candidate address is wave-uniform -> scalar
// loads through K$; 8 candidates batched per lgkmcnt wait. Partial top-8
// per slice merged through LDS, then sum of sqrt distances reduced.
__global__ __launch_bounds__(256) void chamfer_kernel(
    const float4* __restrict__ pred4, const float4* __restrict__ tgt4,
    float* __restrict__ out) {
  int blk = blockIdx.x;           // 1024 blocks
  int dir = blk >> 9;             // 0: pred->tgt, 1: tgt->pred
  int batch = (blk >> 7) & 3;     // 4 batches
  int chunk = blk & 127;          // 128 chunks of 64 queries
  const float4* __restrict__ qarr = (dir == 0 ? pred4 : tgt4) + batch * N;
  const float4* __restrict__ parr = (dir == 0 ? tgt4 : pred4) + batch * N;

  int lane = threadIdx.x & 63;
  int wave = threadIdx.x >> 6;

  float4 q = qarr[chunk * QPB + lane];
  const float4* __restrict__ p0 = parr + wave * L;

  float d[KNN];
#pragma unroll
  for (int i = 0; i < KNN; ++i) d[i] = INFINITY;

  for (int j = 0; j < L; j += 8) {
    float t[8];
#pragma unroll
    for (int u = 0; u < 8; ++u) {
      float4 p = p0[j + u];  // wave-uniform -> s_load, batched
      t[u] = __builtin_fmaf(-q.x, p.x,
             __builtin_fmaf(-q.y, p.y,
             __builtin_fmaf(-q.z, p.z, p.w)));
    }
#pragma unroll
    for (int u = 0; u < 8; ++u) {
      float tv = t[u];
      if (tv < d[KNN - 1]) {  // exec-mask skip when no lane improves
#pragma unroll
        for (int i = KNN - 1; i > 0; --i) d[i] = fminf(d[i], fmaxf(d[i - 1], tv));
        d[0] = fminf(d[0], tv);
      }
    }
  }

  // merge 4 slices' top-8 per query through LDS (stride 9 -> conflict-free)
  __shared__ float part[SLICES][QPB][KNN + 1];
#pragma unroll
  for (int i = 0; i < KNN; ++i) part[wave][lane][i] = d[i];
  __syncthreads();

  if (wave == 0) {
    float m[KNN];
#pragma unroll
    for (int i = 0; i < KNN; ++i) m[i] = INFINITY;
    for (int s = 0; s < SLICES; ++s) {
#pragma unroll
      for (int i = 0; i < KNN; ++i) {
        float tv = part[s][lane][i];
        if (tv < m[KNN - 1]) {
#pragma unroll
          for (int k = KNN - 1; k > 0; --k) m[k] = fminf(m[k], fmaxf(m[k - 1], tv));
          m[0] = fminf(m[0], tv);
        }
      }
    }
    float q2 = 2.0f * q.w;
    float s_ = 0.0f;
#pragma unroll
    for (int i = 0; i < KNN; ++i) {
      float d2 = fmaxf(__builtin_fmaf(2.0f, m[i], q2), 0.0f);
      s_ += sqrtf(d2);
    }
    float val = s_ * (1.0f / KNN);
    for (int off = 32; off; off >>= 1) val += __shfl_down(val, off, 64);
    if (lane == 0) atomicAdd(out, val * (1.0f / (B * N)));
  }
}

extern "C" void kernel_launch(void* const* d_in, const int* in_sizes, int n_in,
                              void* d_out, int out_size, void* d_ws, size_t ws_size,
                              hipStream_t stream) {
  const float* src = (const float*)d_in[0];
  const float* tgt = (const float*)d_in[1];
  const float* flow = (const float*)d_in[2];
  float* out = (float*)d_out;
  float4* pred4 = (float4*)d_ws;
  float4* tgt4 = pred4 + B * N;

  hipMemsetAsync(d_out, 0, sizeof(float), stream);
  prep_kernel<<<(B * N) / 256, 256, 0, stream>>>(src, tgt, flow, pred4, tgt4);
  chamfer_kernel<<<2 * B * (N / QPB), 256, 0, stream>>>(pred4, tgt4, out);
}

// Round 3
// 292.674 us; speedup vs baseline: 2.9263x; 1.1438x over previous
//
#include <hip/hip_runtime.h>
#include <math.h>

constexpr int B = 4;
constexpr int N = 8192;
constexpr int KNN = 8;
constexpr int SLICES = 8;      // candidate slices == waves per block
constexpr int QPB = 64;        // queries per block (one per lane)
constexpr int L = N / SLICES;  // 1024 candidates per slice

// compare-exchange: arr[a] <- min, arr[b] <- max
#define CE(arr, a, b)                              \
  {                                                \
    float lo_ = fminf(arr[a], arr[b]);             \
    float hi_ = fmaxf(arr[a], arr[b]);             \
    arr[a] = lo_;                                  \
    arr[b] = hi_;                                  \
  }

// Prologue: pack pred = src+flow and target as float4 (x, y, z, |p|^2/2).
// Also zeroes the output accumulator (harness poisons it before each call).
__global__ __launch_bounds__(256) void prep_kernel(
    const float* __restrict__ src, const float* __restrict__ tgt,
    const float* __restrict__ flow, float4* __restrict__ pred4,
    float4* __restrict__ tgt4, float* __restrict__ out) {
  int i = blockIdx.x * 256 + threadIdx.x;
  if (i == 0) out[0] = 0.0f;
  if (i >= B * N) return;
  float px = src[3 * i + 0] + flow[3 * i + 0];
  float py = src[3 * i + 1] + flow[3 * i + 1];
  float pz = src[3 * i + 2] + flow[3 * i + 2];
  pred4[i] = make_float4(px, py, pz, 0.5f * (px * px + py * py + pz * pz));
  float tx = tgt[3 * i + 0];
  float ty = tgt[3 * i + 1];
  float tz = tgt[3 * i + 2];
  tgt4[i] = make_float4(tx, ty, tz, 0.5f * (tx * tx + ty * ty + tz * tz));
}

// Block = 8 waves of 64 lanes. Wave w streams candidate slice w (1024 cands,
// wave-uniform scalar loads) for 64 queries (one per lane). Top-8 per lane is
// maintained BRANCHLESSLY: per batch of 8 candidates, sort the 8 keys with a
// 19-CE network, merge with the sorted running top-8 via the bitonic
// lowest-8 trick, 12-CE bitonic cleanup. Fixed ~102 VALU inst / 8 cands.
__global__ __launch_bounds__(512, 8) void chamfer_kernel(
    const float4* __restrict__ pred4, const float4* __restrict__ tgt4,
    float* __restrict__ out) {
  int blk = blockIdx.x;           // 1024 blocks
  int dir = blk >> 9;             // 0: pred->tgt, 1: tgt->pred
  int batch = (blk >> 7) & 3;     // 4 batches
  int chunk = blk & 127;          // 128 chunks of 64 queries
  const float4* __restrict__ qarr = (dir == 0 ? pred4 : tgt4) + batch * N;
  const float4* __restrict__ parr = (dir == 0 ? tgt4 : pred4) + batch * N;

  int lane = threadIdx.x & 63;
  int wave = threadIdx.x >> 6;

  float4 q = qarr[chunk * QPB + lane];
  float nqx = -q.x, nqy = -q.y, nqz = -q.z;
  const float4* __restrict__ p0 = parr + wave * L;

  float d[KNN];
#pragma unroll
  for (int i = 0; i < KNN; ++i) d[i] = INFINITY;

  for (int j = 0; j < L; j += 8) {
    float t[8];
#pragma unroll
    for (int u = 0; u < 8; ++u) {
      float4 p = p0[j + u];  // wave-uniform -> s_load, batched
      float pw = p.w;
      t[u] = __builtin_fmaf(nqx, p.x,
             __builtin_fmaf(nqy, p.y,
             __builtin_fmaf(nqz, p.z, pw)));
    }
    // sort t[0..7] ascending — Batcher odd-even mergesort, 19 CE
    CE(t, 0, 1) CE(t, 2, 3) CE(t, 4, 5) CE(t, 6, 7)
    CE(t, 0, 2) CE(t, 1, 3) CE(t, 4, 6) CE(t, 5, 7)
    CE(t, 1, 2) CE(t, 5, 6)
    CE(t, 0, 4) CE(t, 1, 5) CE(t, 2, 6) CE(t, 3, 7)
    CE(t, 2, 4) CE(t, 3, 5)
    CE(t, 1, 2) CE(t, 3, 4) CE(t, 5, 6)
    // lowest-8 of (d asc, t asc): d[i] = min(d[i], t[7-i]) -> bitonic
#pragma unroll
    for (int i = 0; i < KNN; ++i) d[i] = fminf(d[i], t[7 - i]);
    // bitonic cleanup (len 8): distances 4, 2, 1 — 12 CE
    CE(d, 0, 4) CE(d, 1, 5) CE(d, 2, 6) CE(d, 3, 7)
    CE(d, 0, 2) CE(d, 1, 3) CE(d, 4, 6) CE(d, 5, 7)
    CE(d, 0, 1) CE(d, 2, 3) CE(d, 4, 5) CE(d, 6, 7)
  }

  // merge 8 slices' sorted top-8 per query through LDS (stride 9, <=2-way)
  __shared__ float part[SLICES][QPB][KNN + 1];
#pragma unroll
  for (int i = 0; i < KNN; ++i) part[wave][lane][i] = d[i];
  __syncthreads();

  if (wave == 0) {
    float m[KNN];
#pragma unroll
    for (int i = 0; i < KNN; ++i) m[i] = part[0][lane][i];  // already sorted
    for (int s = 1; s < SLICES; ++s) {
#pragma unroll
      for (int i = 0; i < KNN; ++i) {
        float tv = part[s][lane][i];
        if (tv < m[KNN - 1]) {
#pragma unroll
          for (int k = KNN - 1; k > 0; --k) m[k] = fminf(m[k], fmaxf(m[k - 1], tv));
          m[0] = fminf(m[0], tv);
        }
      }
    }
    float q2 = 2.0f * q.w;
    float s_ = 0.0f;
#pragma unroll
    for (int i = 0; i < KNN; ++i) {
      float d2 = fmaxf(__builtin_fmaf(2.0f, m[i], q2), 0.0f);
      s_ += sqrtf(d2);
    }
    float val = s_ * (1.0f / KNN);
    for (int off = 32; off; off >>= 1) val += __shfl_down(val, off, 64);
    if (lane == 0) atomicAdd(out, val * (1.0f / (B * N)));
  }
}

extern "C" void kernel_launch(void* const* d_in, const int* in_sizes, int n_in,
                              void* d_out, int out_size, void* d_ws, size_t ws_size,
                              hipStream_t stream) {
  const float* src = (const float*)d_in[0];
  const float* tgt = (const float*)d_in[1];
  const float* flow = (const float*)d_in[2];
  float* out = (float*)d_out;
  float4* pred4 = (float4*)d_ws;
  float4* tgt4 = pred4 + B * N;

  prep_kernel<<<(B * N) / 256, 256, 0, stream>>>(src, tgt, flow, pred4, tgt4, out);
  chamfer_kernel<<<2 * B * (N / QPB), 512, 0, stream>>>(pred4, tgt4, out);
}